// Round 1
// baseline (10975.441 us; speedup 1.0000x reference)
//
#include <hip/hip_runtime.h>
#include <math.h>

#define B_  32
#define S_  64
#define T_  64
#define P_  768
#define E_  512
#define H2_ 256
#define G2_ 1024
#define HD_ 512
#define GD_ 2048
#define V_  32000

__device__ __forceinline__ float sigf(float x) {
    return 1.0f / (1.0f + __expf(-x));
}
__device__ __forceinline__ float tanh_fast(float x) {
    // tanh(x) = 1 - 2/(exp(2x)+1); exact limits at +-inf
    return 1.0f - 2.0f / (__expf(2.0f * x) + 1.0f);
}

// ---------------------------------------------------------------------------
// prep: transpose Whh_f/Whh_b to [k][gate]; concat Wih_d|Whh_d rows; tokens
// ---------------------------------------------------------------------------
__global__ void k_prep(const int* __restrict__ ys,
                       const float* __restrict__ Whh_f, const float* __restrict__ Whh_b,
                       const float* __restrict__ Wih_d, const float* __restrict__ Whh_d,
                       float* __restrict__ WhhT_f, float* __restrict__ WhhT_b,
                       float* __restrict__ Wd_cat, int* __restrict__ tokens)
{
    int i = blockIdx.x * blockDim.x + threadIdx.x;
    int n = gridDim.x * blockDim.x;
    for (int idx = i; idx < G2_ * H2_; idx += n) {
        int k = idx / G2_, g = idx % G2_;
        WhhT_f[idx] = Whh_f[g * H2_ + k];
        WhhT_b[idx] = Whh_b[g * H2_ + k];
    }
    for (int idx = i; idx < GD_ * 1024; idx += n) {
        int rw = idx / 1024, k = idx % 1024;
        Wd_cat[idx] = (k < 512) ? Wih_d[rw * 512 + k] : Whh_d[rw * 512 + (k - 512)];
    }
    for (int idx = i; idx < T_ * B_; idx += n) {
        int t = idx / B_, b = idx % B_;
        tokens[idx] = (t == 0) ? 1 : ys[b * (T_ + 1) + t];
    }
}

// ---------------------------------------------------------------------------
// Tiled fp32 GEMM:  C[m,n] = bias[n] + sum_k A(m)[k] * W[n*ldw + woff + k]
// A(m) = gidx ? A + gidx[m]*lda : A + m*lda.  M%64==0, N%64==0, K%16==0.
// ---------------------------------------------------------------------------
__global__ __launch_bounds__(256)
void gemm_f32(const float* __restrict__ A, const int* __restrict__ gidx, int lda,
              const float* __restrict__ W, int ldw, int woff,
              const float* __restrict__ bias,
              float* __restrict__ C, int ldc, int K)
{
    __shared__ __align__(16) float As[16][64];
    __shared__ __align__(16) float Bs[16][64];
    const int m0 = blockIdx.y * 64;
    const int n0 = blockIdx.x * 64;
    const int tid = threadIdx.x;
    const int tm = tid & 15, tn = tid >> 4;
    const int la_m = tid >> 2;        // 0..63
    const int la_k = (tid & 3) * 4;   // 0,4,8,12
    float acc[4][4] = {};

    const int am = m0 + la_m;
    const float* arow = A + (long)(gidx ? gidx[am] : am) * lda;
    const float* wrow = W + (long)(n0 + la_m) * ldw + woff;

    for (int k0 = 0; k0 < K; k0 += 16) {
        float4 av = *(const float4*)(arow + k0 + la_k);
        float4 wv = *(const float4*)(wrow + k0 + la_k);
        As[la_k + 0][la_m] = av.x; As[la_k + 1][la_m] = av.y;
        As[la_k + 2][la_m] = av.z; As[la_k + 3][la_m] = av.w;
        Bs[la_k + 0][la_m] = wv.x; Bs[la_k + 1][la_m] = wv.y;
        Bs[la_k + 2][la_m] = wv.z; Bs[la_k + 3][la_m] = wv.w;
        __syncthreads();
        #pragma unroll
        for (int kk = 0; kk < 16; kk++) {
            float4 a = *(const float4*)&As[kk][tm * 4];
            float4 b = *(const float4*)&Bs[kk][tn * 4];
            acc[0][0] += a.x * b.x; acc[0][1] += a.x * b.y; acc[0][2] += a.x * b.z; acc[0][3] += a.x * b.w;
            acc[1][0] += a.y * b.x; acc[1][1] += a.y * b.y; acc[1][2] += a.y * b.z; acc[1][3] += a.y * b.w;
            acc[2][0] += a.z * b.x; acc[2][1] += a.z * b.y; acc[2][2] += a.z * b.z; acc[2][3] += a.z * b.w;
            acc[3][0] += a.w * b.x; acc[3][1] += a.w * b.y; acc[3][2] += a.w * b.z; acc[3][3] += a.w * b.w;
        }
        __syncthreads();
    }
    float b0 = bias ? bias[n0 + tn * 4 + 0] : 0.f;
    float b1 = bias ? bias[n0 + tn * 4 + 1] : 0.f;
    float b2 = bias ? bias[n0 + tn * 4 + 2] : 0.f;
    float b3 = bias ? bias[n0 + tn * 4 + 3] : 0.f;
    #pragma unroll
    for (int i = 0; i < 4; i++) {
        long m = m0 + tm * 4 + i;
        float4 o = make_float4(acc[i][0] + b0, acc[i][1] + b1, acc[i][2] + b2, acc[i][3] + b3);
        *(float4*)&C[m * ldc + n0 + tn * 4] = o;
    }
}

// ---------------------------------------------------------------------------
// BiLSTM encoder recurrence: one WG per (b, dir); 1024 threads (one per gate).
// gpre has x@Wih.T + b folded.  WhhT is [k][gate].
// ---------------------------------------------------------------------------
__global__ __launch_bounds__(1024)
void k_encoder(const float* __restrict__ gpre_f, const float* __restrict__ gpre_b,
               const float* __restrict__ WhhT_f, const float* __restrict__ WhhT_b,
               const int* __restrict__ x_lens,
               float* __restrict__ enc, float* __restrict__ hid, float* __restrict__ xh0)
{
    const int b   = blockIdx.x >> 1;
    const int dir = blockIdx.x & 1;
    const float* gpre = dir ? gpre_b : gpre_f;
    const float* WT   = dir ? WhhT_b : WhhT_f;
    const int len = x_lens[b];
    __shared__ float h_lds[H2_];
    __shared__ float g_lds[G2_];
    const int tid = threadIdx.x;
    float c = 0.f;
    if (tid < H2_) h_lds[tid] = 0.f;
    __syncthreads();

    for (int t = 0; t < S_; t++) {
        bool valid = t < len;
        if (valid) {
            int s_in = dir ? (len - 1 - t) : t;
            float acc = gpre[(long)(b * S_ + s_in) * G2_ + tid];
            #pragma unroll 8
            for (int k = 0; k < H2_; k++)
                acc += h_lds[k] * WT[k * G2_ + tid];
            g_lds[tid] = acc;
            __syncthreads();
            if (tid < H2_) {
                float gi = g_lds[tid], gf = g_lds[H2_ + tid];
                float gg = g_lds[2 * H2_ + tid], go = g_lds[3 * H2_ + tid];
                c = sigf(gf) * c + sigf(gi) * tanh_fast(gg);
                float hn = sigf(go) * tanh_fast(c);
                h_lds[tid] = hn;
                enc[(long)(b * S_ + s_in) * E_ + dir * H2_ + tid] = hn;
            }
            __syncthreads();
        } else {
            if (tid < H2_)
                enc[(long)(b * S_ + t) * E_ + dir * H2_ + tid] = 0.f;
        }
    }
    if (tid < H2_) {
        hid[b * 1024 + dir * H2_ + tid]       = h_lds[tid]; // h
        hid[b * 1024 + 512 + dir * H2_ + tid] = c;          // c
        xh0[b * 1024 + 512 + dir * H2_ + tid] = h_lds[tid]; // h for gates step 0
    }
}

// ---------------------------------------------------------------------------
// Small-M (M=32) GEMV-GEMM:  C[b, n] = act(bias[n] + add[b,n] + sum_k A[b,k]*W[n*ldw+woff+k])
// grid = N/16 blocks x 256 threads; thread = (b = tid&31, tn = tid>>5), 2 n each.
// ---------------------------------------------------------------------------
__global__ __launch_bounds__(256)
void gemv32(const float* __restrict__ A, int lda, int K,
            const float* __restrict__ W, int ldw, int woff,
            const float* __restrict__ bias, const float* __restrict__ add, int addld,
            float* __restrict__ Cout, int ldc, int do_relu)
{
    __shared__ float a_lds[32][257];
    const int tid = threadIdx.x;
    const int b = tid & 31, tn = tid >> 5;
    const int n0 = blockIdx.x * 16 + tn * 2;
    float acc0 = 0.f, acc1 = 0.f;
    const float* w0 = W + (long)n0 * ldw + woff;
    const float* w1 = w0 + ldw;

    for (int kc = 0; kc < K; kc += 256) {
        for (int i = tid; i < 32 * 256; i += 256) {
            int bb = i >> 8, kk = i & 255;
            a_lds[bb][kk] = A[bb * lda + kc + kk];
        }
        __syncthreads();
        #pragma unroll 8
        for (int k = 0; k < 256; k++) {
            float a = a_lds[b][k];
            acc0 += a * w0[kc + k];
            acc1 += a * w1[kc + k];
        }
        __syncthreads();
    }
    float r0 = acc0 + (bias ? bias[n0]     : 0.f) + (add ? add[b * addld + n0]     : 0.f);
    float r1 = acc1 + (bias ? bias[n0 + 1] : 0.f) + (add ? add[b * addld + n0 + 1] : 0.f);
    if (do_relu) { r0 = fmaxf(r0, 0.f); r1 = fmaxf(r1, 0.f); }
    Cout[b * ldc + n0]     = r0;
    Cout[b * ldc + n0 + 1] = r1;
}

// ---------------------------------------------------------------------------
// Attention scores + softmax + context, one WG per batch element.
// ---------------------------------------------------------------------------
__global__ __launch_bounds__(256)
void k_attn2(const float* __restrict__ enc, const float* __restrict__ enc_proj,
             const float* __restrict__ attq, const float* __restrict__ v_attn,
             const int* __restrict__ x_lens, float* __restrict__ ctx)
{
    const int b = blockIdx.x;
    __shared__ float aq[512];
    __shared__ float part[64][4];
    __shared__ float p_lds[64];
    const int tid = threadIdx.x;
    aq[tid] = attq[b * 512 + tid];
    aq[256 + tid] = attq[b * 512 + 256 + tid];
    __syncthreads();

    const int s = tid >> 2, q = tid & 3;
    const float* ep = enc_proj + (long)(b * S_ + s) * 512;
    float acc = 0.f;
    #pragma unroll 4
    for (int i = 0; i < 128; i++) {
        int e = q + 4 * i;
        acc += v_attn[e] * tanh_fast(ep[e] + aq[e]);
    }
    part[s][q] = acc;
    __syncthreads();
    if (tid < 64) {
        float sc = part[tid][0] + part[tid][1] + part[tid][2] + part[tid][3];
        int len = x_lens[b];
        if (tid >= len) sc = -1e9f;
        float m = sc;
        for (int off = 32; off; off >>= 1) m = fmaxf(m, __shfl_xor(m, off));
        float e = __expf(sc - m);
        float sum = e;
        for (int off = 32; off; off >>= 1) sum += __shfl_xor(sum, off);
        p_lds[tid] = e / sum;
    }
    __syncthreads();
    float c0 = 0.f, c1 = 0.f;
    for (int s2 = 0; s2 < 64; s2++) {
        float p = p_lds[s2];
        const float* er = enc + (long)(b * S_ + s2) * 512;
        c0 += p * er[tid];
        c1 += p * er[256 + tid];
    }
    ctx[b * 512 + tid] = c0;
    ctx[b * 512 + 256 + tid] = c1;
}

// ---------------------------------------------------------------------------
// Decoder gates + state update. grid = 128 WGs (4 hidden each, x4 gate types).
// Reads xh_in = [xi | h_t]; writes h_{t+1} into xh_next[:,512:] (no intra-kernel race),
// h,c into hid, h into H_all.
// ---------------------------------------------------------------------------
__global__ __launch_bounds__(256)
void k_gatesupd(const float* __restrict__ xh_in, const float* __restrict__ Wd_cat,
                const float* __restrict__ b_d, float* __restrict__ hid,
                float* __restrict__ xh_next, float* __restrict__ H_all, int t)
{
    const int jc = blockIdx.x;  // 0..127
    const int tid = threadIdx.x;
    const int b = tid & 31, rh = tid >> 5;  // rows rh*2, rh*2+1 (local 0..15)
    __shared__ float a_lds[32][257];
    __shared__ float g_lds[16][33];
    const int lr0 = rh * 2, lr1 = rh * 2 + 1;
    const int row0 = jc * 4 + (lr0 & 3) + 512 * (lr0 >> 2);
    const int row1 = jc * 4 + (lr1 & 3) + 512 * (lr1 >> 2);
    const float* w0 = Wd_cat + (long)row0 * 1024;
    const float* w1 = Wd_cat + (long)row1 * 1024;
    float acc0 = 0.f, acc1 = 0.f;

    for (int kc = 0; kc < 1024; kc += 256) {
        for (int i = tid; i < 32 * 256; i += 256) {
            int bb = i >> 8, kk = i & 255;
            a_lds[bb][kk] = xh_in[bb * 1024 + kc + kk];
        }
        __syncthreads();
        #pragma unroll 8
        for (int k = 0; k < 256; k++) {
            float a = a_lds[b][k];
            acc0 += a * w0[kc + k];
            acc1 += a * w1[kc + k];
        }
        __syncthreads();
    }
    g_lds[lr0][b] = acc0;
    g_lds[lr1][b] = acc1;
    __syncthreads();
    if (tid < 128) {
        int bb = tid & 31, jl = tid >> 5;  // jl 0..3
        int j = jc * 4 + jl;
        float gi = g_lds[jl][bb]      + b_d[j];
        float gf = g_lds[jl + 4][bb]  + b_d[512 + j];
        float gg = g_lds[jl + 8][bb]  + b_d[1024 + j];
        float go = g_lds[jl + 12][bb] + b_d[1536 + j];
        float c_old = hid[bb * 1024 + 512 + j];
        float c_new = sigf(gf) * c_old + sigf(gi) * tanh_fast(gg);
        float h_new = sigf(go) * tanh_fast(c_new);
        hid[bb * 1024 + j] = h_new;
        hid[bb * 1024 + 512 + j] = c_new;
        xh_next[bb * 1024 + 512 + j] = h_new;
        H_all[(long)(bb * T_ + t) * 512 + j] = h_new;
    }
}

// ---------------------------------------------------------------------------
// Per-row logsumexp over V=32000 logits (one WG per row).
// ---------------------------------------------------------------------------
__global__ __launch_bounds__(256)
void k_lse(const float* __restrict__ Cl, float* __restrict__ lse)
{
    const int r = blockIdx.x;
    const float* row = Cl + (long)r * V_;
    const int tid = threadIdx.x;
    __shared__ float red[4];
    float m = -1e30f;
    for (int i = tid; i < V_; i += 256) m = fmaxf(m, row[i]);
    for (int off = 32; off; off >>= 1) m = fmaxf(m, __shfl_xor(m, off));
    int w = tid >> 6;
    if ((tid & 63) == 0) red[w] = m;
    __syncthreads();
    m = fmaxf(fmaxf(red[0], red[1]), fmaxf(red[2], red[3]));
    __syncthreads();
    float s = 0.f;
    for (int i = tid; i < V_; i += 256) s += __expf(row[i] - m);
    for (int off = 32; off; off >>= 1) s += __shfl_xor(s, off);
    if ((tid & 63) == 0) red[w] = s;
    __syncthreads();
    if (tid == 0) {
        s = red[0] + red[1] + red[2] + red[3];
        lse[r] = m + __logf(s);
    }
}

__global__ void k_logsub(float* __restrict__ C, const float* __restrict__ lse)
{
    long n4 = (long)2048 * V_ / 4;
    long stride = (long)gridDim.x * blockDim.x;
    for (long i = (long)blockIdx.x * blockDim.x + threadIdx.x; i < n4; i += stride) {
        float4 v = ((float4*)C)[i];
        float l = lse[(i * 4) / V_];
        v.x -= l; v.y -= l; v.z -= l; v.w -= l;
        ((float4*)C)[i] = v;
    }
}

// ---------------------------------------------------------------------------
extern "C" void kernel_launch(void* const* d_in, const int* in_sizes, int n_in,
                              void* d_out, int out_size, void* d_ws, size_t ws_size,
                              hipStream_t stream)
{
    const int*   xs     = (const int*)  d_in[0];
    const int*   x_lens = (const int*)  d_in[1];
    const int*   ys     = (const int*)  d_in[2];
    const float* src_emb= (const float*)d_in[3];
    const float* W_tr   = (const float*)d_in[4];
    const float* b_tr   = (const float*)d_in[5];
    const float* Wih_f  = (const float*)d_in[6];
    const float* Whh_f  = (const float*)d_in[7];
    const float* b_f    = (const float*)d_in[8];
    const float* Wih_b  = (const float*)d_in[9];
    const float* Whh_b  = (const float*)d_in[10];
    const float* b_b    = (const float*)d_in[11];
    const float* W_attn = (const float*)d_in[12];
    const float* b_attn = (const float*)d_in[13];
    const float* v_attn = (const float*)d_in[14];
    const float* tgt_emb= (const float*)d_in[15];
    const float* W_comb = (const float*)d_in[16];
    const float* b_comb = (const float*)d_in[17];
    // 18,19,20 = Wih_d, Whh_d, b_d
    const float* Wih_d  = (const float*)d_in[18];
    const float* Whh_d  = (const float*)d_in[19];
    const float* b_d    = (const float*)d_in[20];
    const float* W_out  = (const float*)d_in[21];
    const float* b_out  = (const float*)d_in[22];
    float* out = (float*)d_out;

    float* ws = (float*)d_ws;
    size_t off = 0;
    auto alloc = [&](size_t n) { float* p = ws + off; off += n; return p; };
    float* x      = alloc(2048 * 512);
    float* gpre_f = alloc(2048 * 1024);
    float* gpre_b = alloc(2048 * 1024);
    float* enc    = alloc(2048 * 512);
    float* encp   = alloc(2048 * 512);
    float* embW   = alloc(2048 * 512);
    float* Hall   = alloc(2048 * 512);
    float* hid    = alloc(32 * 1024);
    float* xh0    = alloc(32 * 1024);
    float* xh1    = alloc(32 * 1024);
    float* attq   = alloc(32 * 512);
    float* ctx    = alloc(32 * 512);
    float* WhhTf  = alloc(256 * 1024);
    float* WhhTb  = alloc(256 * 1024);
    float* Wdcat  = alloc(2048 * 1024);
    float* lse    = alloc(2048);
    int*   tokens = (int*)alloc(2048);
    (void)ws_size; (void)n_in; (void)in_sizes; (void)out_size;

    // prep
    k_prep<<<512, 256, 0, stream>>>(ys, Whh_f, Whh_b, Wih_d, Whh_d, WhhTf, WhhTb, Wdcat, tokens);

    // x = src_emb[xs] @ W_tr.T + b_tr   (M=2048, N=512, K=768)
    gemm_f32<<<dim3(512 / 64, 2048 / 64), 256, 0, stream>>>(src_emb, xs, P_, W_tr, P_, 0, b_tr, x, 512, P_);
    // gpre_f/b = x @ Wih.T + b          (M=2048, N=1024, K=512)
    gemm_f32<<<dim3(1024 / 64, 2048 / 64), 256, 0, stream>>>(x, nullptr, 512, Wih_f, 512, 0, b_f, gpre_f, 1024, 512);
    gemm_f32<<<dim3(1024 / 64, 2048 / 64), 256, 0, stream>>>(x, nullptr, 512, Wih_b, 512, 0, b_b, gpre_b, 1024, 512);

    // encoder recurrence
    k_encoder<<<64, 1024, 0, stream>>>(gpre_f, gpre_b, WhhTf, WhhTb, x_lens, enc, hid, xh0);

    // enc_proj = enc @ W_e.T            (W_attn cols 1024:1536, no bias)
    gemm_f32<<<dim3(512 / 64, 2048 / 64), 256, 0, stream>>>(enc, nullptr, 512, W_attn, 1536, 1024, nullptr, encp, 512, 512);
    // embW = tgt_emb[tokens] @ W_comb[:, :512].T + b_comb   (rows = t*32+b)
    gemm_f32<<<dim3(512 / 64, 2048 / 64), 256, 0, stream>>>(tgt_emb, tokens, 512, W_comb, 1024, 0, b_comb, embW, 512, 512);

    // decoder recurrence
    for (int t = 0; t < T_; t++) {
        float* xh_cur  = (t & 1) ? xh1 : xh0;
        float* xh_next = (t & 1) ? xh0 : xh1;
        // attq = hid @ W_h.T + b_attn    (N=512, K=1024)
        gemv32<<<32, 256, 0, stream>>>(hid, 1024, 1024, W_attn, 1536, 0, b_attn, nullptr, 0, attq, 512, 0);
        // scores/softmax/ctx
        k_attn2<<<32, 256, 0, stream>>>(enc, encp, attq, v_attn, x_lens, ctx);
        // xi = relu(embW[t] + ctx @ W_comb[:, 512:].T)  -> xh_cur[:, :512]
        gemv32<<<32, 256, 0, stream>>>(ctx, 512, 512, W_comb, 1024, 512, nullptr,
                                       embW + (size_t)t * 32 * 512, 512, xh_cur, 1024, 1);
        // gates + update
        k_gatesupd<<<128, 256, 0, stream>>>(xh_cur, Wdcat, b_d, hid, xh_next, Hall, t);
    }

    // logits = Hall @ W_out.T + b_out  -> d_out   (M=2048, N=32000, K=512)
    gemm_f32<<<dim3(V_ / 64, 2048 / 64), 256, 0, stream>>>(Hall, nullptr, 512, W_out, 512, 0, b_out, out, V_, 512);
    // log_softmax
    k_lse<<<2048, 256, 0, stream>>>(out, lse);
    k_logsub<<<8192, 256, 0, stream>>>(out, lse);
}